// Round 6
// baseline (261.979 us; speedup 1.0000x reference)
//
#include <hip/hip_runtime.h>
#include <hip/hip_bf16.h>

// MHA: B=4 T=2048 C=1024 H=16 D=64, fp32 in/out, bf16 MFMA internally.
// R14: MEASUREMENT round. attn_kernel and proj have never appeared in the
//      top-5 counter window (QKV's ~76us instances fill all 5 slots);
//      5 rounds of blind theory produced no confirmed win. Split QKV into
//      two M-halves (768 blocks each, 3 blocks/CU, zero tail -> ~39us
//      dispatches) so the true slowest kernel surfaces WITH counters.
//      Everything else identical to R13 (prep fusion, R8 attn, proj64).

typedef unsigned short u16;
typedef __bf16 bf16_t;
typedef bf16_t bf16x8 __attribute__((ext_vector_type(8)));
typedef float f32x4 __attribute__((ext_vector_type(4)));
typedef u16 u16x8 __attribute__((ext_vector_type(8)));
typedef const __attribute__((address_space(1))) void* as1cv;
typedef __attribute__((address_space(3))) void* as3v;

#define BB 4
#define TT 2048
#define CC 1024
#define HH 16
#define DD 64

static __device__ __forceinline__ u16 f2bf(float f) {
  union { float f; unsigned int u; } x; x.f = f;
  unsigned int u = x.u;
  u += 0x7fff + ((u >> 16) & 1);   // round-to-nearest-even
  return (u16)(u >> 16);
}

// pack two f32 -> two bf16 (truncation) in one v_perm_b32
static __device__ __forceinline__ unsigned int pack2(float lo, float hi) {
  return __builtin_amdgcn_perm(__float_as_uint(hi), __float_as_uint(lo),
                               0x07060302u);
}

// ---------------- fused prep: x cast + w_qkv^T + w_proj^T ------------------
// blocks [0,8192): cast x (fp32->bf16, 4/thread)
// blocks [8192,11264): transpose+cast w_qkv [1024][3072] -> [3072][1024]
// blocks [11264,12288): transpose+cast w_proj [1024][1024] -> [1024][1024]
__global__ __launch_bounds__(256) void prep(
    const float* __restrict__ x, u16* __restrict__ xb,
    const float* __restrict__ w_qkv, u16* __restrict__ wqkvT,
    const float* __restrict__ w_proj, u16* __restrict__ wprojT) {
  __shared__ float tile[32][33];
  const int id = blockIdx.x;
  if (id < 8192) {
    int i = (id * 256 + threadIdx.x) * 4;
    float4 v = *(const float4*)(x + i);
    ushort4 o;
    o.x = f2bf(v.x); o.y = f2bf(v.y); o.z = f2bf(v.z); o.w = f2bf(v.w);
    *(ushort4*)(xb + i) = o;
    return;
  }
  const float* in; u16* out; int N, n0, k0;
  if (id < 11264) {
    int i = id - 8192;
    in = w_qkv; out = wqkvT; N = 3072;
    n0 = (i % 96) * 32; k0 = (i / 96) * 32;
  } else {
    int i = id - 11264;
    in = w_proj; out = wprojT; N = 1024;
    n0 = (i & 31) * 32; k0 = (i >> 5) * 32;
  }
  const int tx = threadIdx.x & 31, ty = threadIdx.x >> 5;  // 32 x 8
#pragma unroll
  for (int i = 0; i < 32; i += 8)
    tile[ty + i][tx] = in[(size_t)(k0 + ty + i) * N + n0 + tx];
  __syncthreads();
#pragma unroll
  for (int i = 0; i < 32; i += 8)
    out[(size_t)(n0 + ty + i) * 1024 + k0 + tx] = f2bf(tile[tx][ty + i]);
}

// ---------------- GEMM: C[M][N] = A[M][K](bf16) * Bt[N][K]^T + bias --------
// BK=64: per round 8 global_load_lds + 2 sub-steps of (8 ds_read_b128 +
// 16 MFMA). LDS phys 16B slot = logical blk ^ (row & 7).
// mb = M-offset (grid covers [mb, mb + gridDim.x*128)).
__global__ __launch_bounds__(256) void gemm_bt(
    const u16* __restrict__ A, const u16* __restrict__ Bt,
    const float* __restrict__ bias,
    int M, int N, int K, int mode, int mb,
    u16* __restrict__ qb, u16* __restrict__ kb, u16* __restrict__ vt,
    float* __restrict__ outf) {
  __shared__ u16 As[128][64];   // 16 KB
  __shared__ u16 Bs[128][64];   // 16 KB
  const int tid = threadIdx.x;
  const int lane = tid & 63, wave = tid >> 6;
  const int quad = lane >> 4, l16 = lane & 15;
  const int wy = wave >> 1, wx = wave & 1;  // 2x2 waves, 64x64 each
  const int m0 = mb + blockIdx.x * 128, n0 = blockIdx.y * 128;
  const int srow = lane >> 3, sblk = (lane & 7) ^ (lane >> 3);  // row&7==srow
  const int rsw = l16 & 7;  // read-side swizzle

  f32x4 acc[4][4] = {};

  for (int k0 = 0; k0 < K; k0 += 64) {
#pragma unroll
    for (int i = 0; i < 4; i++) {
      int lr = wave * 32 + i * 8;          // lds row base (mult of 8)
      int row = lr + srow;
      __builtin_amdgcn_global_load_lds(
          (as1cv)(A + (size_t)(m0 + row) * K + k0 + sblk * 8),
          (as3v)(&As[lr][0]), 16, 0, 0);
      __builtin_amdgcn_global_load_lds(
          (as1cv)(Bt + (size_t)(n0 + row) * K + k0 + sblk * 8),
          (as3v)(&Bs[lr][0]), 16, 0, 0);
    }
    __syncthreads();
#pragma unroll
    for (int ks = 0; ks < 2; ks++) {
      const int pcol = ((ks * 4 + quad) ^ rsw) * 8;
      bf16x8 af[4], bfr[4];
#pragma unroll
      for (int i = 0; i < 4; i++)
        af[i] = *(const bf16x8*)&As[wy * 64 + i * 16 + l16][pcol];
#pragma unroll
      for (int j = 0; j < 4; j++)
        bfr[j] = *(const bf16x8*)&Bs[wx * 64 + j * 16 + l16][pcol];
#pragma unroll
      for (int i = 0; i < 4; i++)
#pragma unroll
        for (int j = 0; j < 4; j++)
          acc[i][j] = __builtin_amdgcn_mfma_f32_16x16x32_bf16(af[i], bfr[j], acc[i][j], 0, 0, 0);
    }
    __syncthreads();
  }

  // epilogue: C/D layout col=lane&15, row=quad*4+reg. Branch is block-uniform.
  if (mode == 1) {
#pragma unroll
    for (int i = 0; i < 4; i++)
#pragma unroll
      for (int j = 0; j < 4; j++) {
        int nn = n0 + wx * 64 + j * 16 + l16;
        float bv = bias[nn];
#pragma unroll
        for (int r = 0; r < 4; r++) {
          int mm = m0 + wy * 64 + i * 16 + quad * 4 + r;
          outf[(size_t)mm * N + nn] = acc[i][j][r] + bv;
        }
      }
  } else {
    const int b = m0 >> 11;                       // batch (block-uniform)
    const int tb = (m0 & 2047) + wy * 64 + quad * 4;
    if (n0 < 1024) {        // ---- Q, pre-scaled by 1/sqrt(d)*log2(e) ----
#pragma unroll
      for (int j = 0; j < 4; j++) {
        int nn = n0 + wx * 64 + j * 16 + l16;
        int h = nn >> 6, dd = nn & 63;
        float bv = bias[nn];
        u16* base = qb + ((size_t)(b * HH + h) * TT) * DD + dd;
#pragma unroll
        for (int i = 0; i < 4; i++)
#pragma unroll
          for (int r = 0; r < 4; r++)
            base[(size_t)(tb + i * 16 + r) * DD] =
                f2bf((acc[i][j][r] + bv) * 0.1803368801111f);
      }
    } else if (n0 < 2048) { // ---- K ----
#pragma unroll
      for (int j = 0; j < 4; j++) {
        int nn = n0 + wx * 64 + j * 16 + l16;
        int rem = nn & 1023, h = rem >> 6, dd = rem & 63;
        float bv = bias[nn];
        u16* base = kb + ((size_t)(b * HH + h) * TT) * DD + dd;
#pragma unroll
        for (int i = 0; i < 4; i++)
#pragma unroll
          for (int r = 0; r < 4; r++)
            base[(size_t)(tb + i * 16 + r) * DD] = f2bf(acc[i][j][r] + bv);
      }
    } else {                // ---- V, stored transposed [B,H,D,T] ----
#pragma unroll
      for (int j = 0; j < 4; j++) {
        int nn = n0 + wx * 64 + j * 16 + l16;
        int rem = nn & 1023, h = rem >> 6, dd = rem & 63;
        float bv = bias[nn];
        u16* base = vt + ((size_t)(b * HH + h) * DD + dd) * TT;
#pragma unroll
        for (int i = 0; i < 4; i++)
#pragma unroll
          for (int r = 0; r < 4; r++)
            base[tb + i * 16 + r] = f2bf(acc[i][j][r] + bv);
      }
    }
  }
}

// ---------------- proj GEMM: BM=64 BN=128 (occupancy variant) --------------
// out[8192][1024] = A[8192][1024](bf16) * Bt[1024][1024]^T + bias, fp32 out.
// Same staging/swizzle as gemm_bt; 24 KB LDS, acc[2][4] -> ~4 resident
// blocks/CU (1024 blocks total) so barrier drains stay TLP-covered.
__global__ __launch_bounds__(256) void gemm_proj64(
    const u16* __restrict__ A, const u16* __restrict__ Bt,
    const float* __restrict__ bias, float* __restrict__ outf) {
  constexpr int N = 1024, K = 1024;
  __shared__ u16 As[64][64];    // 8 KB
  __shared__ u16 Bs[128][64];   // 16 KB
  const int tid = threadIdx.x;
  const int lane = tid & 63, wave = tid >> 6;
  const int quad = lane >> 4, l16 = lane & 15;
  const int wy = wave >> 1, wx = wave & 1;  // 2x2 waves, 32x64 each
  const int m0 = blockIdx.x * 64, n0 = blockIdx.y * 128;
  const int srow = lane >> 3, sblk = (lane & 7) ^ (lane >> 3);  // row&7==srow
  const int rsw = l16 & 7;  // read-side swizzle

  f32x4 acc[2][4] = {};

  for (int k0 = 0; k0 < K; k0 += 64) {
#pragma unroll
    for (int i = 0; i < 2; i++) {        // A: 64 rows
      int lr = wave * 16 + i * 8;
      __builtin_amdgcn_global_load_lds(
          (as1cv)(A + (size_t)(m0 + lr + srow) * K + k0 + sblk * 8),
          (as3v)(&As[lr][0]), 16, 0, 0);
    }
#pragma unroll
    for (int i = 0; i < 4; i++) {        // B: 128 rows
      int lr = wave * 32 + i * 8;
      __builtin_amdgcn_global_load_lds(
          (as1cv)(Bt + (size_t)(n0 + lr + srow) * K + k0 + sblk * 8),
          (as3v)(&Bs[lr][0]), 16, 0, 0);
    }
    __syncthreads();
#pragma unroll
    for (int ks = 0; ks < 2; ks++) {
      const int pcol = ((ks * 4 + quad) ^ rsw) * 8;
      bf16x8 af[2], bfr[4];
#pragma unroll
      for (int i = 0; i < 2; i++)
        af[i] = *(const bf16x8*)&As[wy * 32 + i * 16 + l16][pcol];
#pragma unroll
      for (int j = 0; j < 4; j++)
        bfr[j] = *(const bf16x8*)&Bs[wx * 64 + j * 16 + l16][pcol];
#pragma unroll
      for (int i = 0; i < 2; i++)
#pragma unroll
        for (int j = 0; j < 4; j++)
          acc[i][j] = __builtin_amdgcn_mfma_f32_16x16x32_bf16(af[i], bfr[j], acc[i][j], 0, 0, 0);
    }
    __syncthreads();
  }

  // epilogue: C/D layout col=lane&15, row=quad*4+reg
#pragma unroll
  for (int i = 0; i < 2; i++)
#pragma unroll
    for (int j = 0; j < 4; j++) {
      int nn = n0 + wx * 64 + j * 16 + l16;
      float bv = bias[nn];
#pragma unroll
      for (int r = 0; r < 4; r++) {
        int mm = m0 + wy * 32 + i * 16 + quad * 4 + r;
        outf[(size_t)mm * N + nn] = acc[i][j][r] + bv;
      }
    }
}

// ---------------- flash attention (block-cooperative, S^T/O^T) -------------
// grid (bh=64, tile=16); block = 4 waves = 128 q rows. kv rounds of 128 =
// two proven 64-kv halves per barrier pair; V read per-c from LDS (no
// register hoist -> no spill). Linear block id === bh (mod 8) -> XCD L2.
__global__ __launch_bounds__(256, 3) void attn_kernel(
    const u16* __restrict__ q_buf, const u16* __restrict__ k_buf,
    const u16* __restrict__ v_t, u16* __restrict__ attn_out) {
  __shared__ __align__(16) u16 Ks[2][64][64];   // K  [kv][d]   16 KB
  __shared__ __align__(16) u16 Vs[2][64][64];   // V^T [d][kv]  16 KB
  __shared__ __align__(16) u16 Pl[4][16][64];   // per-wave P [q][kv] 8 KB
  const int tid = threadIdx.x;
  const int lane = tid & 63, wave = tid >> 6;
  const int quad = lane >> 4, l16 = lane & 15;
  const int bh = blockIdx.x;
  const int b = bh >> 4, h = bh & 15;
  const int tile = 15 - (int)blockIdx.y;        // heavy tiles dispatch first
  const int qt0 = tile * 128;
  const int qw = qt0 + wave * 32;               // wave's first q row
  const u16* Q = q_buf + (size_t)bh * TT * DD;
  const u16* Kp = k_buf + (size_t)bh * TT * DD;
  const u16* Vt = v_t + (size_t)bh * DD * TT;

  // staging geometry: lane -> (row group l>>3, 16B blk (l&7)^(l>>3))
  const int srow = lane >> 3;
  const int sblk = (lane & 7) ^ srow;
  const int swz = l16 & 7;                      // fragment-read swizzle

  bf16x8 qf[2][2];
#pragma unroll
  for (int f = 0; f < 2; f++)
#pragma unroll
    for (int h2 = 0; h2 < 2; h2++)
      qf[f][h2] = *(const bf16x8*)(Q + (size_t)(qw + f * 16 + l16) * DD + h2 * 32 + quad * 8);

  f32x4 o[2][4] = {};   // O^T[d = g*16+quad*4+r][q = l16]
  float l_p[2] = {0.f, 0.f};

  const int my_end = qw + 32;
  const int kv_stop = qt0 + 128;
  for (int kv0 = 0; kv0 < kv_stop; kv0 += 128) {
    // ---- stage both 64-kv halves: K rows and V^T cols ----
#pragma unroll
    for (int hh = 0; hh < 2; hh++)
#pragma unroll
      for (int i = 0; i < 2; i++) {
        int r = wave * 16 + i * 8 + srow;       // lds row 0..63 (row&7==srow)
        __builtin_amdgcn_global_load_lds(
            (as1cv)(Kp + (size_t)(kv0 + hh * 64 + r) * DD + sblk * 8),
            (as3v)(&Ks[hh][wave * 16 + i * 8][0]), 16, 0, 0);
        __builtin_amdgcn_global_load_lds(
            (as1cv)(Vt + (size_t)r * TT + kv0 + hh * 64 + sblk * 8),
            (as3v)(&Vs[hh][wave * 16 + i * 8][0]), 16, 0, 0);
      }
    __syncthreads();

#pragma unroll
    for (int hh = 0; hh < 2; hh++) {
      const int kb0 = kv0 + hh * 64;
      if (kb0 < my_end) {                       // wave-uniform causal skip
        const bool edge = (kb0 + 63 > qw);
        // ---- S^T = K * Q^T ----
        f32x4 s[2][4] = {};
#pragma unroll
        for (int kg = 0; kg < 4; kg++) {
          bf16x8 ka = *(const bf16x8*)&Ks[hh][kg * 16 + l16][(quad ^ swz) * 8];
          bf16x8 kb2 = *(const bf16x8*)&Ks[hh][kg * 16 + l16][((4 + quad) ^ swz) * 8];
#pragma unroll
          for (int f = 0; f < 2; f++) {
            s[f][kg] = __builtin_amdgcn_mfma_f32_16x16x32_bf16(ka, qf[f][0], s[f][kg], 0, 0, 0);
            s[f][kg] = __builtin_amdgcn_mfma_f32_16x16x32_bf16(kb2, qf[f][1], s[f][kg], 0, 0, 0);
          }
        }
        // ---- softmax (fixed-max exp2) + P store + PV ----
#pragma unroll
        for (int f = 0; f < 2; f++) {
          const int qi = qw + f * 16 + l16;
#pragma unroll
          for (int kg = 0; kg < 4; kg++) {
            float v0 = s[f][kg][0], v1 = s[f][kg][1], v2 = s[f][kg][2], v3 = s[f][kg][3];
            if (edge) {
              int kvb = kb0 + kg * 16 + quad * 4;
              v0 = (kvb + 0 <= qi) ? v0 : -1e30f;
              v1 = (kvb + 1 <= qi) ? v1 : -1e30f;
              v2 = (kvb + 2 <= qi) ? v2 : -1e30f;
              v3 = (kvb + 3 <= qi) ? v3 : -1e30f;
            }
            float e0 = __builtin_amdgcn_exp2f(v0);
            float e1 = __builtin_amdgcn_exp2f(v1);
            float e2 = __builtin_amdgcn_exp2f(v2);
            float e3 = __builtin_amdgcn_exp2f(v3);
            l_p[f] += (e0 + e1) + (e2 + e3);
            uint2 pk;
            pk.x = pack2(e0, e1);
            pk.y = pack2(e2, e3);
            // P[q=l16][kv]: 16B blk = kg*2+(quad>>1), swizzled; 8B half = quad&1
            *(uint2*)&Pl[wave][l16][((kg * 2 + (quad >> 1)) ^ swz) * 8 + (quad & 1) * 4] = pk;
          }
          __threadfence_block();                // same-wave DS write->read order
#pragma unroll
          for (int c = 0; c < 2; c++) {
            bf16x8 pa = *(const bf16x8*)&Pl[wave][l16][((c * 4 + quad) ^ swz) * 8];
#pragma unroll
            for (int g = 0; g < 4; g++) {
              bf16x8 vr = *(const bf16x8*)&Vs[hh][g * 16 + l16][((c * 4 + quad) ^ swz) * 8];
              o[f][g] = __builtin_amdgcn_mfma_f32_16x16x32_bf16(vr, pa, o[f][g], 0, 0, 0);
            }
          }
        }
      }
    }
    __syncthreads();
  }

  // epilogue: reduce l across quads, scale, vectorized store
#pragma unroll
  for (int f = 0; f < 2; f++) {
    float l = l_p[f];
    l += __shfl_xor(l, 16);
    l += __shfl_xor(l, 32);
    float inv_l = 1.0f / l;
    int trow = qw + f * 16 + l16;
#pragma unroll
    for (int g = 0; g < 4; g++) {
      ushort4 st;
      st.x = f2bf(o[f][g][0] * inv_l);
      st.y = f2bf(o[f][g][1] * inv_l);
      st.z = f2bf(o[f][g][2] * inv_l);
      st.w = f2bf(o[f][g][3] * inv_l);
      *(ushort4*)(attn_out + ((size_t)(b * TT + trow)) * CC + h * DD + g * 16 + quad * 4) = st;
    }
  }
}

extern "C" void kernel_launch(void* const* d_in, const int* in_sizes, int n_in,
                              void* d_out, int out_size, void* d_ws, size_t ws_size,
                              hipStream_t stream) {
  const float* x = (const float*)d_in[0];
  const float* w_qkv = (const float*)d_in[1];
  const float* b_qkv = (const float*)d_in[2];
  const float* w_proj = (const float*)d_in[3];
  const float* b_proj = (const float*)d_in[4];
  float* out = (float*)d_out;
  char* ws = (char*)d_ws;

  // workspace layout (72 MB total); xb aliases ao (xb dead before attn runs)
  u16* wqkvT = (u16*)(ws);                    // 3072*1024*2 = 6291456
  u16* wprojT = (u16*)(ws + 6291456);         // 1024*1024*2 = 2097152
  u16* qb = (u16*)(ws + 8388608);             // [B,H,T,D] bf16, 16 MB
  u16* kb = (u16*)(ws + 25165824);            // [B,H,T,D] bf16, 16 MB
  u16* vt = (u16*)(ws + 41943040);            // [B,H,D,T] bf16, 16 MB
  u16* ao = (u16*)(ws + 58720256);            // [B,T,C]   bf16, 16 MB
  u16* xb = ao;                               // x cast to bf16 (aliased)

  prep<<<dim3(12288), 256, 0, stream>>>(x, xb, w_qkv, wqkvT, w_proj, wprojT);
  gemm_bt<<<dim3(32, 24), 256, 0, stream>>>(xb, wqkvT, b_qkv, 8192, 3072, 1024, 0, 0,
                                            qb, kb, vt, nullptr);
  gemm_bt<<<dim3(32, 24), 256, 0, stream>>>(xb, wqkvT, b_qkv, 8192, 3072, 1024, 0, 4096,
                                            qb, kb, vt, nullptr);
  attn_kernel<<<dim3(64, 16), 256, 0, stream>>>(qb, kb, vt, ao);
  gemm_proj64<<<dim3(128, 8), 256, 0, stream>>>(ao, wprojT, b_proj, out);
}

// Round 7
// 251.430 us; speedup vs baseline: 1.0420x; 1.0420x over previous
//
#include <hip/hip_runtime.h>
#include <hip/hip_bf16.h>

// MHA: B=4 T=2048 C=1024 H=16 D=64, fp32 in/out, bf16 MFMA internally.
// R15: R14 measured attn = 59.8us, Occupancy 26%, VALUBusy 44% > Mfma 24%,
//      bank-conflict 2.16M (~6%). 26% occupancy = tile load imbalance:
//      block-group work sums per CU were 40 vs 28 units. Fix: tile =
//      perm[blockIdx.y], perm groups {15,14,13,12|0,1,2,3|11,10,9,8|
//      4,5,6,7} -> every CU's 4 groups sum to 34 units; heavy still first.
//      Re-merge QKV into one (64,24) dispatch (the R14 M-split cost ~10us
//      of ramp/tail; it was measurement-only). proj64 + prep kept.

typedef unsigned short u16;
typedef __bf16 bf16_t;
typedef bf16_t bf16x8 __attribute__((ext_vector_type(8)));
typedef float f32x4 __attribute__((ext_vector_type(4)));
typedef u16 u16x8 __attribute__((ext_vector_type(8)));
typedef const __attribute__((address_space(1))) void* as1cv;
typedef __attribute__((address_space(3))) void* as3v;

#define BB 4
#define TT 2048
#define CC 1024
#define HH 16
#define DD 64

static __device__ __forceinline__ u16 f2bf(float f) {
  union { float f; unsigned int u; } x; x.f = f;
  unsigned int u = x.u;
  u += 0x7fff + ((u >> 16) & 1);   // round-to-nearest-even
  return (u16)(u >> 16);
}

// pack two f32 -> two bf16 (truncation) in one v_perm_b32
static __device__ __forceinline__ unsigned int pack2(float lo, float hi) {
  return __builtin_amdgcn_perm(__float_as_uint(hi), __float_as_uint(lo),
                               0x07060302u);
}

// ---------------- fused prep: x cast + w_qkv^T + w_proj^T ------------------
// blocks [0,8192): cast x (fp32->bf16, 4/thread)
// blocks [8192,11264): transpose+cast w_qkv [1024][3072] -> [3072][1024]
// blocks [11264,12288): transpose+cast w_proj [1024][1024] -> [1024][1024]
__global__ __launch_bounds__(256) void prep(
    const float* __restrict__ x, u16* __restrict__ xb,
    const float* __restrict__ w_qkv, u16* __restrict__ wqkvT,
    const float* __restrict__ w_proj, u16* __restrict__ wprojT) {
  __shared__ float tile[32][33];
  const int id = blockIdx.x;
  if (id < 8192) {
    int i = (id * 256 + threadIdx.x) * 4;
    float4 v = *(const float4*)(x + i);
    ushort4 o;
    o.x = f2bf(v.x); o.y = f2bf(v.y); o.z = f2bf(v.z); o.w = f2bf(v.w);
    *(ushort4*)(xb + i) = o;
    return;
  }
  const float* in; u16* out; int N, n0, k0;
  if (id < 11264) {
    int i = id - 8192;
    in = w_qkv; out = wqkvT; N = 3072;
    n0 = (i % 96) * 32; k0 = (i / 96) * 32;
  } else {
    int i = id - 11264;
    in = w_proj; out = wprojT; N = 1024;
    n0 = (i & 31) * 32; k0 = (i >> 5) * 32;
  }
  const int tx = threadIdx.x & 31, ty = threadIdx.x >> 5;  // 32 x 8
#pragma unroll
  for (int i = 0; i < 32; i += 8)
    tile[ty + i][tx] = in[(size_t)(k0 + ty + i) * N + n0 + tx];
  __syncthreads();
#pragma unroll
  for (int i = 0; i < 32; i += 8)
    out[(size_t)(n0 + ty + i) * 1024 + k0 + tx] = f2bf(tile[tx][ty + i]);
}

// ---------------- GEMM: C[M][N] = A[M][K](bf16) * Bt[N][K]^T + bias --------
// BK=64: per round 8 global_load_lds + 2 sub-steps of (8 ds_read_b128 +
// 16 MFMA). LDS phys 16B slot = logical blk ^ (row & 7).
__global__ __launch_bounds__(256) void gemm_bt(
    const u16* __restrict__ A, const u16* __restrict__ Bt,
    const float* __restrict__ bias,
    int M, int N, int K, int mode,
    u16* __restrict__ qb, u16* __restrict__ kb, u16* __restrict__ vt,
    float* __restrict__ outf) {
  __shared__ u16 As[128][64];   // 16 KB
  __shared__ u16 Bs[128][64];   // 16 KB
  const int tid = threadIdx.x;
  const int lane = tid & 63, wave = tid >> 6;
  const int quad = lane >> 4, l16 = lane & 15;
  const int wy = wave >> 1, wx = wave & 1;  // 2x2 waves, 64x64 each
  const int m0 = blockIdx.x * 128, n0 = blockIdx.y * 128;
  const int srow = lane >> 3, sblk = (lane & 7) ^ (lane >> 3);  // row&7==srow
  const int rsw = l16 & 7;  // read-side swizzle

  f32x4 acc[4][4] = {};

  for (int k0 = 0; k0 < K; k0 += 64) {
#pragma unroll
    for (int i = 0; i < 4; i++) {
      int lr = wave * 32 + i * 8;          // lds row base (mult of 8)
      int row = lr + srow;
      __builtin_amdgcn_global_load_lds(
          (as1cv)(A + (size_t)(m0 + row) * K + k0 + sblk * 8),
          (as3v)(&As[lr][0]), 16, 0, 0);
      __builtin_amdgcn_global_load_lds(
          (as1cv)(Bt + (size_t)(n0 + row) * K + k0 + sblk * 8),
          (as3v)(&Bs[lr][0]), 16, 0, 0);
    }
    __syncthreads();
#pragma unroll
    for (int ks = 0; ks < 2; ks++) {
      const int pcol = ((ks * 4 + quad) ^ rsw) * 8;
      bf16x8 af[4], bfr[4];
#pragma unroll
      for (int i = 0; i < 4; i++)
        af[i] = *(const bf16x8*)&As[wy * 64 + i * 16 + l16][pcol];
#pragma unroll
      for (int j = 0; j < 4; j++)
        bfr[j] = *(const bf16x8*)&Bs[wx * 64 + j * 16 + l16][pcol];
#pragma unroll
      for (int i = 0; i < 4; i++)
#pragma unroll
        for (int j = 0; j < 4; j++)
          acc[i][j] = __builtin_amdgcn_mfma_f32_16x16x32_bf16(af[i], bfr[j], acc[i][j], 0, 0, 0);
    }
    __syncthreads();
  }

  // epilogue: C/D layout col=lane&15, row=quad*4+reg. Branch is block-uniform.
  if (mode == 1) {
#pragma unroll
    for (int i = 0; i < 4; i++)
#pragma unroll
      for (int j = 0; j < 4; j++) {
        int nn = n0 + wx * 64 + j * 16 + l16;
        float bv = bias[nn];
#pragma unroll
        for (int r = 0; r < 4; r++) {
          int mm = m0 + wy * 64 + i * 16 + quad * 4 + r;
          outf[(size_t)mm * N + nn] = acc[i][j][r] + bv;
        }
      }
  } else {
    const int b = m0 >> 11;                       // batch (block-uniform)
    const int tb = (m0 & 2047) + wy * 64 + quad * 4;
    if (n0 < 1024) {        // ---- Q, pre-scaled by 1/sqrt(d)*log2(e) ----
#pragma unroll
      for (int j = 0; j < 4; j++) {
        int nn = n0 + wx * 64 + j * 16 + l16;
        int h = nn >> 6, dd = nn & 63;
        float bv = bias[nn];
        u16* base = qb + ((size_t)(b * HH + h) * TT) * DD + dd;
#pragma unroll
        for (int i = 0; i < 4; i++)
#pragma unroll
          for (int r = 0; r < 4; r++)
            base[(size_t)(tb + i * 16 + r) * DD] =
                f2bf((acc[i][j][r] + bv) * 0.1803368801111f);
      }
    } else if (n0 < 2048) { // ---- K ----
#pragma unroll
      for (int j = 0; j < 4; j++) {
        int nn = n0 + wx * 64 + j * 16 + l16;
        int rem = nn & 1023, h = rem >> 6, dd = rem & 63;
        float bv = bias[nn];
        u16* base = kb + ((size_t)(b * HH + h) * TT) * DD + dd;
#pragma unroll
        for (int i = 0; i < 4; i++)
#pragma unroll
          for (int r = 0; r < 4; r++)
            base[(size_t)(tb + i * 16 + r) * DD] = f2bf(acc[i][j][r] + bv);
      }
    } else {                // ---- V, stored transposed [B,H,D,T] ----
#pragma unroll
      for (int j = 0; j < 4; j++) {
        int nn = n0 + wx * 64 + j * 16 + l16;
        int rem = nn & 1023, h = rem >> 6, dd = rem & 63;
        float bv = bias[nn];
        u16* base = vt + ((size_t)(b * HH + h) * DD + dd) * TT;
#pragma unroll
        for (int i = 0; i < 4; i++)
#pragma unroll
          for (int r = 0; r < 4; r++)
            base[tb + i * 16 + r] = f2bf(acc[i][j][r] + bv);
      }
    }
  }
}

// ---------------- proj GEMM: BM=64 BN=128 (occupancy variant) --------------
// out[8192][1024] = A[8192][1024](bf16) * Bt[1024][1024]^T + bias, fp32 out.
__global__ __launch_bounds__(256) void gemm_proj64(
    const u16* __restrict__ A, const u16* __restrict__ Bt,
    const float* __restrict__ bias, float* __restrict__ outf) {
  constexpr int N = 1024, K = 1024;
  __shared__ u16 As[64][64];    // 8 KB
  __shared__ u16 Bs[128][64];   // 16 KB
  const int tid = threadIdx.x;
  const int lane = tid & 63, wave = tid >> 6;
  const int quad = lane >> 4, l16 = lane & 15;
  const int wy = wave >> 1, wx = wave & 1;  // 2x2 waves, 32x64 each
  const int m0 = blockIdx.x * 64, n0 = blockIdx.y * 128;
  const int srow = lane >> 3, sblk = (lane & 7) ^ (lane >> 3);  // row&7==srow
  const int rsw = l16 & 7;  // read-side swizzle

  f32x4 acc[2][4] = {};

  for (int k0 = 0; k0 < K; k0 += 64) {
#pragma unroll
    for (int i = 0; i < 2; i++) {        // A: 64 rows
      int lr = wave * 16 + i * 8;
      __builtin_amdgcn_global_load_lds(
          (as1cv)(A + (size_t)(m0 + lr + srow) * K + k0 + sblk * 8),
          (as3v)(&As[lr][0]), 16, 0, 0);
    }
#pragma unroll
    for (int i = 0; i < 4; i++) {        // B: 128 rows
      int lr = wave * 32 + i * 8;
      __builtin_amdgcn_global_load_lds(
          (as1cv)(Bt + (size_t)(n0 + lr + srow) * K + k0 + sblk * 8),
          (as3v)(&Bs[lr][0]), 16, 0, 0);
    }
    __syncthreads();
#pragma unroll
    for (int ks = 0; ks < 2; ks++) {
      const int pcol = ((ks * 4 + quad) ^ rsw) * 8;
      bf16x8 af[2], bfr[4];
#pragma unroll
      for (int i = 0; i < 2; i++)
        af[i] = *(const bf16x8*)&As[wy * 32 + i * 16 + l16][pcol];
#pragma unroll
      for (int j = 0; j < 4; j++)
        bfr[j] = *(const bf16x8*)&Bs[wx * 64 + j * 16 + l16][pcol];
#pragma unroll
      for (int i = 0; i < 2; i++)
#pragma unroll
        for (int j = 0; j < 4; j++)
          acc[i][j] = __builtin_amdgcn_mfma_f32_16x16x32_bf16(af[i], bfr[j], acc[i][j], 0, 0, 0);
    }
    __syncthreads();
  }

  // epilogue: C/D layout col=lane&15, row=quad*4+reg
#pragma unroll
  for (int i = 0; i < 2; i++)
#pragma unroll
    for (int j = 0; j < 4; j++) {
      int nn = n0 + wx * 64 + j * 16 + l16;
      float bv = bias[nn];
#pragma unroll
      for (int r = 0; r < 4; r++) {
        int mm = m0 + wy * 32 + i * 16 + quad * 4 + r;
        outf[(size_t)mm * N + nn] = acc[i][j][r] + bv;
      }
    }
}

// ---------------- flash attention (block-cooperative, S^T/O^T) -------------
// grid (bh=64, ty=16); block = 4 waves = 128 q rows. kv rounds of 128 =
// two proven 64-kv halves per barrier pair. Tile chosen via balanced perm:
// CU block-groups {g,g+4,g+8,g+12} all sum to 34 work units (R14: 26%
// occupancy from 40-vs-28 imbalance). Heavy tiles still dispatch first.
__global__ __launch_bounds__(256, 3) void attn_kernel(
    const u16* __restrict__ q_buf, const u16* __restrict__ k_buf,
    const u16* __restrict__ v_t, u16* __restrict__ attn_out) {
  __shared__ __align__(16) u16 Ks[2][64][64];   // K  [kv][d]   16 KB
  __shared__ __align__(16) u16 Vs[2][64][64];   // V^T [d][kv]  16 KB
  __shared__ __align__(16) u16 Pl[4][16][64];   // per-wave P [q][kv] 8 KB
  const int tid = threadIdx.x;
  const int lane = tid & 63, wave = tid >> 6;
  const int quad = lane >> 4, l16 = lane & 15;
  const int bh = blockIdx.x;
  const int b = bh >> 4, h = bh & 15;
  // balanced tile permutation: groups of 4 consecutive y sum to 34 units
  const int perm16[16] = {15,14,13,12, 0,1,2,3, 11,10,9,8, 4,5,6,7};
  const int tile = perm16[blockIdx.y];
  const int qt0 = tile * 128;
  const int qw = qt0 + wave * 32;               // wave's first q row
  const u16* Q = q_buf + (size_t)bh * TT * DD;
  const u16* Kp = k_buf + (size_t)bh * TT * DD;
  const u16* Vt = v_t + (size_t)bh * DD * TT;

  // staging geometry: lane -> (row group l>>3, 16B blk (l&7)^(l>>3))
  const int srow = lane >> 3;
  const int sblk = (lane & 7) ^ srow;
  const int swz = l16 & 7;                      // fragment-read swizzle

  bf16x8 qf[2][2];
#pragma unroll
  for (int f = 0; f < 2; f++)
#pragma unroll
    for (int h2 = 0; h2 < 2; h2++)
      qf[f][h2] = *(const bf16x8*)(Q + (size_t)(qw + f * 16 + l16) * DD + h2 * 32 + quad * 8);

  f32x4 o[2][4] = {};   // O^T[d = g*16+quad*4+r][q = l16]
  float l_p[2] = {0.f, 0.f};

  const int my_end = qw + 32;
  const int kv_stop = qt0 + 128;
  for (int kv0 = 0; kv0 < kv_stop; kv0 += 128) {
    // ---- stage both 64-kv halves: K rows and V^T cols ----
#pragma unroll
    for (int hh = 0; hh < 2; hh++)
#pragma unroll
      for (int i = 0; i < 2; i++) {
        int r = wave * 16 + i * 8 + srow;       // lds row 0..63 (row&7==srow)
        __builtin_amdgcn_global_load_lds(
            (as1cv)(Kp + (size_t)(kv0 + hh * 64 + r) * DD + sblk * 8),
            (as3v)(&Ks[hh][wave * 16 + i * 8][0]), 16, 0, 0);
        __builtin_amdgcn_global_load_lds(
            (as1cv)(Vt + (size_t)r * TT + kv0 + hh * 64 + sblk * 8),
            (as3v)(&Vs[hh][wave * 16 + i * 8][0]), 16, 0, 0);
      }
    __syncthreads();

#pragma unroll
    for (int hh = 0; hh < 2; hh++) {
      const int kb0 = kv0 + hh * 64;
      if (kb0 < my_end) {                       // wave-uniform causal skip
        const bool edge = (kb0 + 63 > qw);
        // ---- S^T = K * Q^T ----
        f32x4 s[2][4] = {};
#pragma unroll
        for (int kg = 0; kg < 4; kg++) {
          bf16x8 ka = *(const bf16x8*)&Ks[hh][kg * 16 + l16][(quad ^ swz) * 8];
          bf16x8 kb2 = *(const bf16x8*)&Ks[hh][kg * 16 + l16][((4 + quad) ^ swz) * 8];
#pragma unroll
          for (int f = 0; f < 2; f++) {
            s[f][kg] = __builtin_amdgcn_mfma_f32_16x16x32_bf16(ka, qf[f][0], s[f][kg], 0, 0, 0);
            s[f][kg] = __builtin_amdgcn_mfma_f32_16x16x32_bf16(kb2, qf[f][1], s[f][kg], 0, 0, 0);
          }
        }
        // ---- softmax (fixed-max exp2) + P store + PV ----
#pragma unroll
        for (int f = 0; f < 2; f++) {
          const int qi = qw + f * 16 + l16;
#pragma unroll
          for (int kg = 0; kg < 4; kg++) {
            float v0 = s[f][kg][0], v1 = s[f][kg][1], v2 = s[f][kg][2], v3 = s[f][kg][3];
            if (edge) {
              int kvb = kb0 + kg * 16 + quad * 4;
              v0 = (kvb + 0 <= qi) ? v0 : -1e30f;
              v1 = (kvb + 1 <= qi) ? v1 : -1e30f;
              v2 = (kvb + 2 <= qi) ? v2 : -1e30f;
              v3 = (kvb + 3 <= qi) ? v3 : -1e30f;
            }
            float e0 = __builtin_amdgcn_exp2f(v0);
            float e1 = __builtin_amdgcn_exp2f(v1);
            float e2 = __builtin_amdgcn_exp2f(v2);
            float e3 = __builtin_amdgcn_exp2f(v3);
            l_p[f] += (e0 + e1) + (e2 + e3);
            uint2 pk;
            pk.x = pack2(e0, e1);
            pk.y = pack2(e2, e3);
            // P[q=l16][kv]: 16B blk = kg*2+(quad>>1), swizzled; 8B half = quad&1
            *(uint2*)&Pl[wave][l16][((kg * 2 + (quad >> 1)) ^ swz) * 8 + (quad & 1) * 4] = pk;
          }
          __threadfence_block();                // same-wave DS write->read order
#pragma unroll
          for (int c = 0; c < 2; c++) {
            bf16x8 pa = *(const bf16x8*)&Pl[wave][l16][((c * 4 + quad) ^ swz) * 8];
#pragma unroll
            for (int g = 0; g < 4; g++) {
              bf16x8 vr = *(const bf16x8*)&Vs[hh][g * 16 + l16][((c * 4 + quad) ^ swz) * 8];
              o[f][g] = __builtin_amdgcn_mfma_f32_16x16x32_bf16(vr, pa, o[f][g], 0, 0, 0);
            }
          }
        }
      }
    }
    __syncthreads();
  }

  // epilogue: reduce l across quads, scale, vectorized store
#pragma unroll
  for (int f = 0; f < 2; f++) {
    float l = l_p[f];
    l += __shfl_xor(l, 16);
    l += __shfl_xor(l, 32);
    float inv_l = 1.0f / l;
    int trow = qw + f * 16 + l16;
#pragma unroll
    for (int g = 0; g < 4; g++) {
      ushort4 st;
      st.x = f2bf(o[f][g][0] * inv_l);
      st.y = f2bf(o[f][g][1] * inv_l);
      st.z = f2bf(o[f][g][2] * inv_l);
      st.w = f2bf(o[f][g][3] * inv_l);
      *(ushort4*)(attn_out + ((size_t)(b * TT + trow)) * CC + h * DD + g * 16 + quad * 4) = st;
    }
  }
}

extern "C" void kernel_launch(void* const* d_in, const int* in_sizes, int n_in,
                              void* d_out, int out_size, void* d_ws, size_t ws_size,
                              hipStream_t stream) {
  const float* x = (const float*)d_in[0];
  const float* w_qkv = (const float*)d_in[1];
  const float* b_qkv = (const float*)d_in[2];
  const float* w_proj = (const float*)d_in[3];
  const float* b_proj = (const float*)d_in[4];
  float* out = (float*)d_out;
  char* ws = (char*)d_ws;

  // workspace layout (72 MB total); xb aliases ao (xb dead before attn runs)
  u16* wqkvT = (u16*)(ws);                    // 3072*1024*2 = 6291456
  u16* wprojT = (u16*)(ws + 6291456);         // 1024*1024*2 = 2097152
  u16* qb = (u16*)(ws + 8388608);             // [B,H,T,D] bf16, 16 MB
  u16* kb = (u16*)(ws + 25165824);            // [B,H,T,D] bf16, 16 MB
  u16* vt = (u16*)(ws + 41943040);            // [B,H,D,T] bf16, 16 MB
  u16* ao = (u16*)(ws + 58720256);            // [B,T,C]   bf16, 16 MB
  u16* xb = ao;                               // x cast to bf16 (aliased)

  prep<<<dim3(12288), 256, 0, stream>>>(x, xb, w_qkv, wqkvT, w_proj, wprojT);
  gemm_bt<<<dim3(64, 24), 256, 0, stream>>>(xb, wqkvT, b_qkv, 8192, 3072, 1024, 0,
                                            qb, kb, vt, nullptr);
  attn_kernel<<<dim3(64, 16), 256, 0, stream>>>(qb, kb, vt, ao);
  gemm_proj64<<<dim3(128, 8), 256, 0, stream>>>(ao, wprojT, b_proj, out);
}

// Round 8
// 236.624 us; speedup vs baseline: 1.1072x; 1.0626x over previous
//
#include <hip/hip_runtime.h>
#include <hip/hip_bf16.h>

// MHA: B=4 T=2048 C=1024 H=16 D=64, fp32 in/out, bf16 MFMA internally.
// R16: attn PV restructure (R14 counters: VALUBusy 44% > Mfma 24%, LDS
//      heavy). (1) P written for BOTH f into per-f buffers -> ONE
//      threadfence per 64-kv block (was 2), then PV with V-fragment reads
//      hoisted across f: ds_read_b128 per block 20 -> 12, PV MFMA runs as
//      8 back-to-back per c. LDS 40->48 KB (still 3 blocks/CU).
//      (2) T5 setprio(1) around QK and PV MFMA clusters (m191: +4-7% attn).
//      QKV gemm_bt, prep, proj64, balanced perm all unchanged.

typedef unsigned short u16;
typedef __bf16 bf16_t;
typedef bf16_t bf16x8 __attribute__((ext_vector_type(8)));
typedef float f32x4 __attribute__((ext_vector_type(4)));
typedef u16 u16x8 __attribute__((ext_vector_type(8)));
typedef const __attribute__((address_space(1))) void* as1cv;
typedef __attribute__((address_space(3))) void* as3v;

#define BB 4
#define TT 2048
#define CC 1024
#define HH 16
#define DD 64

static __device__ __forceinline__ u16 f2bf(float f) {
  union { float f; unsigned int u; } x; x.f = f;
  unsigned int u = x.u;
  u += 0x7fff + ((u >> 16) & 1);   // round-to-nearest-even
  return (u16)(u >> 16);
}

// pack two f32 -> two bf16 (truncation) in one v_perm_b32
static __device__ __forceinline__ unsigned int pack2(float lo, float hi) {
  return __builtin_amdgcn_perm(__float_as_uint(hi), __float_as_uint(lo),
                               0x07060302u);
}

// ---------------- fused prep: x cast + w_qkv^T + w_proj^T ------------------
// blocks [0,8192): cast x (fp32->bf16, 4/thread)
// blocks [8192,11264): transpose+cast w_qkv [1024][3072] -> [3072][1024]
// blocks [11264,12288): transpose+cast w_proj [1024][1024] -> [1024][1024]
__global__ __launch_bounds__(256) void prep(
    const float* __restrict__ x, u16* __restrict__ xb,
    const float* __restrict__ w_qkv, u16* __restrict__ wqkvT,
    const float* __restrict__ w_proj, u16* __restrict__ wprojT) {
  __shared__ float tile[32][33];
  const int id = blockIdx.x;
  if (id < 8192) {
    int i = (id * 256 + threadIdx.x) * 4;
    float4 v = *(const float4*)(x + i);
    ushort4 o;
    o.x = f2bf(v.x); o.y = f2bf(v.y); o.z = f2bf(v.z); o.w = f2bf(v.w);
    *(ushort4*)(xb + i) = o;
    return;
  }
  const float* in; u16* out; int N, n0, k0;
  if (id < 11264) {
    int i = id - 8192;
    in = w_qkv; out = wqkvT; N = 3072;
    n0 = (i % 96) * 32; k0 = (i / 96) * 32;
  } else {
    int i = id - 11264;
    in = w_proj; out = wprojT; N = 1024;
    n0 = (i & 31) * 32; k0 = (i >> 5) * 32;
  }
  const int tx = threadIdx.x & 31, ty = threadIdx.x >> 5;  // 32 x 8
#pragma unroll
  for (int i = 0; i < 32; i += 8)
    tile[ty + i][tx] = in[(size_t)(k0 + ty + i) * N + n0 + tx];
  __syncthreads();
#pragma unroll
  for (int i = 0; i < 32; i += 8)
    out[(size_t)(n0 + ty + i) * 1024 + k0 + tx] = f2bf(tile[tx][ty + i]);
}

// ---------------- GEMM: C[M][N] = A[M][K](bf16) * Bt[N][K]^T + bias --------
// BK=64: per round 8 global_load_lds + 2 sub-steps of (8 ds_read_b128 +
// 16 MFMA). LDS phys 16B slot = logical blk ^ (row & 7).
__global__ __launch_bounds__(256) void gemm_bt(
    const u16* __restrict__ A, const u16* __restrict__ Bt,
    const float* __restrict__ bias,
    int M, int N, int K, int mode,
    u16* __restrict__ qb, u16* __restrict__ kb, u16* __restrict__ vt,
    float* __restrict__ outf) {
  __shared__ u16 As[128][64];   // 16 KB
  __shared__ u16 Bs[128][64];   // 16 KB
  const int tid = threadIdx.x;
  const int lane = tid & 63, wave = tid >> 6;
  const int quad = lane >> 4, l16 = lane & 15;
  const int wy = wave >> 1, wx = wave & 1;  // 2x2 waves, 64x64 each
  const int m0 = blockIdx.x * 128, n0 = blockIdx.y * 128;
  const int srow = lane >> 3, sblk = (lane & 7) ^ (lane >> 3);  // row&7==srow
  const int rsw = l16 & 7;  // read-side swizzle

  f32x4 acc[4][4] = {};

  for (int k0 = 0; k0 < K; k0 += 64) {
#pragma unroll
    for (int i = 0; i < 4; i++) {
      int lr = wave * 32 + i * 8;          // lds row base (mult of 8)
      int row = lr + srow;
      __builtin_amdgcn_global_load_lds(
          (as1cv)(A + (size_t)(m0 + row) * K + k0 + sblk * 8),
          (as3v)(&As[lr][0]), 16, 0, 0);
      __builtin_amdgcn_global_load_lds(
          (as1cv)(Bt + (size_t)(n0 + row) * K + k0 + sblk * 8),
          (as3v)(&Bs[lr][0]), 16, 0, 0);
    }
    __syncthreads();
#pragma unroll
    for (int ks = 0; ks < 2; ks++) {
      const int pcol = ((ks * 4 + quad) ^ rsw) * 8;
      bf16x8 af[4], bfr[4];
#pragma unroll
      for (int i = 0; i < 4; i++)
        af[i] = *(const bf16x8*)&As[wy * 64 + i * 16 + l16][pcol];
#pragma unroll
      for (int j = 0; j < 4; j++)
        bfr[j] = *(const bf16x8*)&Bs[wx * 64 + j * 16 + l16][pcol];
#pragma unroll
      for (int i = 0; i < 4; i++)
#pragma unroll
        for (int j = 0; j < 4; j++)
          acc[i][j] = __builtin_amdgcn_mfma_f32_16x16x32_bf16(af[i], bfr[j], acc[i][j], 0, 0, 0);
    }
    __syncthreads();
  }

  // epilogue: C/D layout col=lane&15, row=quad*4+reg. Branch is block-uniform.
  if (mode == 1) {
#pragma unroll
    for (int i = 0; i < 4; i++)
#pragma unroll
      for (int j = 0; j < 4; j++) {
        int nn = n0 + wx * 64 + j * 16 + l16;
        float bv = bias[nn];
#pragma unroll
        for (int r = 0; r < 4; r++) {
          int mm = m0 + wy * 64 + i * 16 + quad * 4 + r;
          outf[(size_t)mm * N + nn] = acc[i][j][r] + bv;
        }
      }
  } else {
    const int b = m0 >> 11;                       // batch (block-uniform)
    const int tb = (m0 & 2047) + wy * 64 + quad * 4;
    if (n0 < 1024) {        // ---- Q, pre-scaled by 1/sqrt(d)*log2(e) ----
#pragma unroll
      for (int j = 0; j < 4; j++) {
        int nn = n0 + wx * 64 + j * 16 + l16;
        int h = nn >> 6, dd = nn & 63;
        float bv = bias[nn];
        u16* base = qb + ((size_t)(b * HH + h) * TT) * DD + dd;
#pragma unroll
        for (int i = 0; i < 4; i++)
#pragma unroll
          for (int r = 0; r < 4; r++)
            base[(size_t)(tb + i * 16 + r) * DD] =
                f2bf((acc[i][j][r] + bv) * 0.1803368801111f);
      }
    } else if (n0 < 2048) { // ---- K ----
#pragma unroll
      for (int j = 0; j < 4; j++) {
        int nn = n0 + wx * 64 + j * 16 + l16;
        int rem = nn & 1023, h = rem >> 6, dd = rem & 63;
        float bv = bias[nn];
        u16* base = kb + ((size_t)(b * HH + h) * TT) * DD + dd;
#pragma unroll
        for (int i = 0; i < 4; i++)
#pragma unroll
          for (int r = 0; r < 4; r++)
            base[(size_t)(tb + i * 16 + r) * DD] = f2bf(acc[i][j][r] + bv);
      }
    } else {                // ---- V, stored transposed [B,H,D,T] ----
#pragma unroll
      for (int j = 0; j < 4; j++) {
        int nn = n0 + wx * 64 + j * 16 + l16;
        int rem = nn & 1023, h = rem >> 6, dd = rem & 63;
        float bv = bias[nn];
        u16* base = vt + ((size_t)(b * HH + h) * DD + dd) * TT;
#pragma unroll
        for (int i = 0; i < 4; i++)
#pragma unroll
          for (int r = 0; r < 4; r++)
            base[tb + i * 16 + r] = f2bf(acc[i][j][r] + bv);
      }
    }
  }
}

// ---------------- proj GEMM: BM=64 BN=128 (occupancy variant) --------------
// out[8192][1024] = A[8192][1024](bf16) * Bt[1024][1024]^T + bias, fp32 out.
__global__ __launch_bounds__(256) void gemm_proj64(
    const u16* __restrict__ A, const u16* __restrict__ Bt,
    const float* __restrict__ bias, float* __restrict__ outf) {
  constexpr int N = 1024, K = 1024;
  __shared__ u16 As[64][64];    // 8 KB
  __shared__ u16 Bs[128][64];   // 16 KB
  const int tid = threadIdx.x;
  const int lane = tid & 63, wave = tid >> 6;
  const int quad = lane >> 4, l16 = lane & 15;
  const int wy = wave >> 1, wx = wave & 1;  // 2x2 waves, 32x64 each
  const int m0 = blockIdx.x * 64, n0 = blockIdx.y * 128;
  const int srow = lane >> 3, sblk = (lane & 7) ^ (lane >> 3);  // row&7==srow
  const int rsw = l16 & 7;  // read-side swizzle

  f32x4 acc[2][4] = {};

  for (int k0 = 0; k0 < K; k0 += 64) {
#pragma unroll
    for (int i = 0; i < 2; i++) {        // A: 64 rows
      int lr = wave * 16 + i * 8;
      __builtin_amdgcn_global_load_lds(
          (as1cv)(A + (size_t)(m0 + lr + srow) * K + k0 + sblk * 8),
          (as3v)(&As[lr][0]), 16, 0, 0);
    }
#pragma unroll
    for (int i = 0; i < 4; i++) {        // B: 128 rows
      int lr = wave * 32 + i * 8;
      __builtin_amdgcn_global_load_lds(
          (as1cv)(Bt + (size_t)(n0 + lr + srow) * K + k0 + sblk * 8),
          (as3v)(&Bs[lr][0]), 16, 0, 0);
    }
    __syncthreads();
#pragma unroll
    for (int ks = 0; ks < 2; ks++) {
      const int pcol = ((ks * 4 + quad) ^ rsw) * 8;
      bf16x8 af[2], bfr[4];
#pragma unroll
      for (int i = 0; i < 2; i++)
        af[i] = *(const bf16x8*)&As[wy * 32 + i * 16 + l16][pcol];
#pragma unroll
      for (int j = 0; j < 4; j++)
        bfr[j] = *(const bf16x8*)&Bs[wx * 64 + j * 16 + l16][pcol];
#pragma unroll
      for (int i = 0; i < 2; i++)
#pragma unroll
        for (int j = 0; j < 4; j++)
          acc[i][j] = __builtin_amdgcn_mfma_f32_16x16x32_bf16(af[i], bfr[j], acc[i][j], 0, 0, 0);
    }
    __syncthreads();
  }

  // epilogue: C/D layout col=lane&15, row=quad*4+reg
#pragma unroll
  for (int i = 0; i < 2; i++)
#pragma unroll
    for (int j = 0; j < 4; j++) {
      int nn = n0 + wx * 64 + j * 16 + l16;
      float bv = bias[nn];
#pragma unroll
      for (int r = 0; r < 4; r++) {
        int mm = m0 + wy * 32 + i * 16 + quad * 4 + r;
        outf[(size_t)mm * N + nn] = acc[i][j][r] + bv;
      }
    }
}

// ---------------- flash attention (block-cooperative, S^T/O^T) -------------
// grid (bh=64, ty=16); block = 4 waves = 128 q rows. kv rounds of 128.
// Balanced tile perm (R15). R16: per-f P buffers -> single fence per 64-kv
// block; PV reads V fragments once (shared across f); setprio on MFMA.
__global__ __launch_bounds__(256, 3) void attn_kernel(
    const u16* __restrict__ q_buf, const u16* __restrict__ k_buf,
    const u16* __restrict__ v_t, u16* __restrict__ attn_out) {
  __shared__ __align__(16) u16 Ks[2][64][64];      // K  [kv][d]   16 KB
  __shared__ __align__(16) u16 Vs[2][64][64];      // V^T [d][kv]  16 KB
  __shared__ __align__(16) u16 Pl[4][2][16][64];   // per-wave per-f P 16 KB
  const int tid = threadIdx.x;
  const int lane = tid & 63, wave = tid >> 6;
  const int quad = lane >> 4, l16 = lane & 15;
  const int bh = blockIdx.x;
  const int b = bh >> 4, h = bh & 15;
  // balanced tile permutation: groups of 4 consecutive y sum to 34 units
  const int perm16[16] = {15,14,13,12, 0,1,2,3, 11,10,9,8, 4,5,6,7};
  const int tile = perm16[blockIdx.y];
  const int qt0 = tile * 128;
  const int qw = qt0 + wave * 32;               // wave's first q row
  const u16* Q = q_buf + (size_t)bh * TT * DD;
  const u16* Kp = k_buf + (size_t)bh * TT * DD;
  const u16* Vt = v_t + (size_t)bh * DD * TT;

  // staging geometry: lane -> (row group l>>3, 16B blk (l&7)^(l>>3))
  const int srow = lane >> 3;
  const int sblk = (lane & 7) ^ srow;
  const int swz = l16 & 7;                      // fragment-read swizzle

  bf16x8 qf[2][2];
#pragma unroll
  for (int f = 0; f < 2; f++)
#pragma unroll
    for (int h2 = 0; h2 < 2; h2++)
      qf[f][h2] = *(const bf16x8*)(Q + (size_t)(qw + f * 16 + l16) * DD + h2 * 32 + quad * 8);

  f32x4 o[2][4] = {};   // O^T[d = g*16+quad*4+r][q = l16]
  float l_p[2] = {0.f, 0.f};

  const int my_end = qw + 32;
  const int kv_stop = qt0 + 128;
  for (int kv0 = 0; kv0 < kv_stop; kv0 += 128) {
    // ---- stage both 64-kv halves: K rows and V^T cols ----
#pragma unroll
    for (int hh = 0; hh < 2; hh++)
#pragma unroll
      for (int i = 0; i < 2; i++) {
        int r = wave * 16 + i * 8 + srow;       // lds row 0..63 (row&7==srow)
        __builtin_amdgcn_global_load_lds(
            (as1cv)(Kp + (size_t)(kv0 + hh * 64 + r) * DD + sblk * 8),
            (as3v)(&Ks[hh][wave * 16 + i * 8][0]), 16, 0, 0);
        __builtin_amdgcn_global_load_lds(
            (as1cv)(Vt + (size_t)r * TT + kv0 + hh * 64 + sblk * 8),
            (as3v)(&Vs[hh][wave * 16 + i * 8][0]), 16, 0, 0);
      }
    __syncthreads();

#pragma unroll
    for (int hh = 0; hh < 2; hh++) {
      const int kb0 = kv0 + hh * 64;
      if (kb0 < my_end) {                       // wave-uniform causal skip
        const bool edge = (kb0 + 63 > qw);
        // ---- S^T = K * Q^T ----
        f32x4 s[2][4] = {};
        __builtin_amdgcn_s_setprio(1);
#pragma unroll
        for (int kg = 0; kg < 4; kg++) {
          bf16x8 ka = *(const bf16x8*)&Ks[hh][kg * 16 + l16][(quad ^ swz) * 8];
          bf16x8 kb2 = *(const bf16x8*)&Ks[hh][kg * 16 + l16][((4 + quad) ^ swz) * 8];
#pragma unroll
          for (int f = 0; f < 2; f++) {
            s[f][kg] = __builtin_amdgcn_mfma_f32_16x16x32_bf16(ka, qf[f][0], s[f][kg], 0, 0, 0);
            s[f][kg] = __builtin_amdgcn_mfma_f32_16x16x32_bf16(kb2, qf[f][1], s[f][kg], 0, 0, 0);
          }
        }
        __builtin_amdgcn_s_setprio(0);
        // ---- softmax (fixed-max exp2) + P store, BOTH f ----
#pragma unroll
        for (int f = 0; f < 2; f++) {
          const int qi = qw + f * 16 + l16;
#pragma unroll
          for (int kg = 0; kg < 4; kg++) {
            float v0 = s[f][kg][0], v1 = s[f][kg][1], v2 = s[f][kg][2], v3 = s[f][kg][3];
            if (edge) {
              int kvb = kb0 + kg * 16 + quad * 4;
              v0 = (kvb + 0 <= qi) ? v0 : -1e30f;
              v1 = (kvb + 1 <= qi) ? v1 : -1e30f;
              v2 = (kvb + 2 <= qi) ? v2 : -1e30f;
              v3 = (kvb + 3 <= qi) ? v3 : -1e30f;
            }
            float e0 = __builtin_amdgcn_exp2f(v0);
            float e1 = __builtin_amdgcn_exp2f(v1);
            float e2 = __builtin_amdgcn_exp2f(v2);
            float e3 = __builtin_amdgcn_exp2f(v3);
            l_p[f] += (e0 + e1) + (e2 + e3);
            uint2 pk;
            pk.x = pack2(e0, e1);
            pk.y = pack2(e2, e3);
            // P[q=l16][kv]: 16B blk = kg*2+(quad>>1), swizzled; 8B half = quad&1
            *(uint2*)&Pl[wave][f][l16][((kg * 2 + (quad >> 1)) ^ swz) * 8 + (quad & 1) * 4] = pk;
          }
        }
        __threadfence_block();                  // one DS write->read fence
        // ---- PV: V fragments shared across f, dense MFMA clusters ----
#pragma unroll
        for (int c = 0; c < 2; c++) {
          bf16x8 pa0 = *(const bf16x8*)&Pl[wave][0][l16][((c * 4 + quad) ^ swz) * 8];
          bf16x8 pa1 = *(const bf16x8*)&Pl[wave][1][l16][((c * 4 + quad) ^ swz) * 8];
          __builtin_amdgcn_s_setprio(1);
#pragma unroll
          for (int g = 0; g < 4; g++) {
            bf16x8 vr = *(const bf16x8*)&Vs[hh][g * 16 + l16][((c * 4 + quad) ^ swz) * 8];
            o[0][g] = __builtin_amdgcn_mfma_f32_16x16x32_bf16(vr, pa0, o[0][g], 0, 0, 0);
            o[1][g] = __builtin_amdgcn_mfma_f32_16x16x32_bf16(vr, pa1, o[1][g], 0, 0, 0);
          }
          __builtin_amdgcn_s_setprio(0);
        }
      }
    }
    __syncthreads();
  }

  // epilogue: reduce l across quads, scale, vectorized store
#pragma unroll
  for (int f = 0; f < 2; f++) {
    float l = l_p[f];
    l += __shfl_xor(l, 16);
    l += __shfl_xor(l, 32);
    float inv_l = 1.0f / l;
    int trow = qw + f * 16 + l16;
#pragma unroll
    for (int g = 0; g < 4; g++) {
      ushort4 st;
      st.x = f2bf(o[f][g][0] * inv_l);
      st.y = f2bf(o[f][g][1] * inv_l);
      st.z = f2bf(o[f][g][2] * inv_l);
      st.w = f2bf(o[f][g][3] * inv_l);
      *(ushort4*)(attn_out + ((size_t)(b * TT + trow)) * CC + h * DD + g * 16 + quad * 4) = st;
    }
  }
}

extern "C" void kernel_launch(void* const* d_in, const int* in_sizes, int n_in,
                              void* d_out, int out_size, void* d_ws, size_t ws_size,
                              hipStream_t stream) {
  const float* x = (const float*)d_in[0];
  const float* w_qkv = (const float*)d_in[1];
  const float* b_qkv = (const float*)d_in[2];
  const float* w_proj = (const float*)d_in[3];
  const float* b_proj = (const float*)d_in[4];
  float* out = (float*)d_out;
  char* ws = (char*)d_ws;

  // workspace layout (72 MB total); xb aliases ao (xb dead before attn runs)
  u16* wqkvT = (u16*)(ws);                    // 3072*1024*2 = 6291456
  u16* wprojT = (u16*)(ws + 6291456);         // 1024*1024*2 = 2097152
  u16* qb = (u16*)(ws + 8388608);             // [B,H,T,D] bf16, 16 MB
  u16* kb = (u16*)(ws + 25165824);            // [B,H,T,D] bf16, 16 MB
  u16* vt = (u16*)(ws + 41943040);            // [B,H,D,T] bf16, 16 MB
  u16* ao = (u16*)(ws + 58720256);            // [B,T,C]   bf16, 16 MB
  u16* xb = ao;                               // x cast to bf16 (aliased)

  prep<<<dim3(12288), 256, 0, stream>>>(x, xb, w_qkv, wqkvT, w_proj, wprojT);
  gemm_bt<<<dim3(64, 24), 256, 0, stream>>>(xb, wqkvT, b_qkv, 8192, 3072, 1024, 0,
                                            qb, kb, vt, nullptr);
  attn_kernel<<<dim3(64, 16), 256, 0, stream>>>(qb, kb, vt, ao);
  gemm_proj64<<<dim3(128, 8), 256, 0, stream>>>(ao, wprojT, b_proj, out);
}